// Round 11
// baseline (224.884 us; speedup 1.0000x reference)
//
#include <hip/hip_runtime.h>
#include <math.h>

// TopKRouter: x[16384,2048] fp32, W[64,2048] fp32
// out: [0..32767] top2 indices (as float), [32768..65535] gates, [65536] aux
// Split-fp16 MFMA (3-term: xh*wh + xh*wl + xl*wh).
// R11 = R10 (single fused kernel, TMB=64, 1 blk/CU, W fp32 direct + in-reg
// cvt, device-ticket aux finalize) with two loop fixes:
//  1. ONE barrier per chunk (dbuf needs only the chunk-head barrier; R7/R10's
//     trailing lgkm+bar was redundant -- 32 exposed sync events removed)
//  2. sched_barrier(0) pins: after the x-refill issue (loads cannot be sunk
//     past the barrier to their use site -- the R3 allocator-collapse
//     mechanism) and after s_barrier (ds_reads cannot hoist above it).
#define NTOK 16384
#define DDIM 2048
#define NEXP 64
#define TMB  64                 // tokens per block (4 MFMA M-tiles)
#define NBLK (NTOK / TMB)       // 256 blocks -> 1 block/CU
#define NCH  32                 // K chunks of 64
#define NS   64                 // K32 MFMA steps total

typedef _Float16 half8v __attribute__((ext_vector_type(8)));
typedef float    f32x4  __attribute__((ext_vector_type(4)));

#define MFMA16(a, b, c) __builtin_amdgcn_mfma_f32_16x16x32_f16((a), (b), (c), 0, 0, 0)

// convert 8 consecutive fp32 -> (high fp16, residual fp16)
__device__ __forceinline__ void cvt8(float4 a, float4 b, half8v& h, half8v& l) {
    h[0]=(_Float16)a.x; l[0]=(_Float16)(a.x-(float)h[0]);
    h[1]=(_Float16)a.y; l[1]=(_Float16)(a.y-(float)h[1]);
    h[2]=(_Float16)a.z; l[2]=(_Float16)(a.z-(float)h[2]);
    h[3]=(_Float16)a.w; l[3]=(_Float16)(a.w-(float)h[3]);
    h[4]=(_Float16)b.x; l[4]=(_Float16)(b.x-(float)h[4]);
    h[5]=(_Float16)b.y; l[5]=(_Float16)(b.y-(float)h[5]);
    h[6]=(_Float16)b.z; l[6]=(_Float16)(b.z-(float)h[6]);
    h[7]=(_Float16)b.w; l[7]=(_Float16)(b.w-(float)h[7]);
}

__global__ __launch_bounds__(256, 1) void router_kernel(
    const float* __restrict__ x, const float* __restrict__ W,
    float* __restrict__ accg, float* __restrict__ out)
{
    __shared__ __align__(16) _Float16 Ah[2][4096];   // 16 KB
    __shared__ __align__(16) _Float16 Al[2][4096];   // 16 KB
    __shared__ float lgt[TMB][NEXP + 1];             // 16.6 KB
    __shared__ float cnt[NEXP];
    __shared__ int lastBlk;

    const int tid  = threadIdx.x;
    const int lane = tid & 63;
    const int wv   = __builtin_amdgcn_readfirstlane(tid >> 6);  // expert block 0..3
    const int m0   = blockIdx.x * TMB;

    if (tid < NEXP) cnt[tid] = 0.0f;

    // ---- staging map: thread t -> row r=t>>2 (0..63), cols c0..c0+15 ----
    const int r    = tid >> 2;
    const int c0   = (tid & 3) * 16;
    const int tile = r >> 4, tok = r & 15;
    const int S0 = c0 >> 5,       q0 = (c0 >> 3) & 3;
    const int S1 = (c0+8) >> 5,   q1 = ((c0+8) >> 3) & 3;
    const int g0 = S0*64 + q0*16 + tok,  g1 = S1*64 + q1*16 + tok;
    const int off0 = tile*1024 + (g0 ^ ((g0>>4)&7)) * 8;
    const int off1 = tile*1024 + (g1 ^ ((g1>>4)&7)) * 8;

    const float* gx = x + (size_t)(m0 + r) * DDIM + c0;

    // ---- read-side swizzled offsets (per tile add tile*1024) ----
    const int gr1 = 64 + lane;
    const int rd0 = (lane ^ ((lane>>4)&7)) * 8;
    const int rd1 = (gr1 ^ ((gr1>>4)&7)) * 8;

    // ---- W direct fp32: B-frag lane (q=lane>>4, nl=lane&15) holds
    // expert e = wv*16+nl, k = Sg*32 + q*8 + j  (prep-layout equivalent) ----
    const float* wfp = W + (size_t)(wv * 16 + (lane & 15)) * DDIM + (lane >> 4) * 8;

    f32x4 acc0 = {0.f,0.f,0.f,0.f}, acc1 = {0.f,0.f,0.f,0.f};
    f32x4 acc2 = {0.f,0.f,0.f,0.f}, acc3 = {0.f,0.f,0.f,0.f};

    // ---- prologue: x ring depth 2 (chunks 0,1); W ring 4 slots (steps 0..3)
    float4 xa0 = *(const float4*)(gx +  0), xa1 = *(const float4*)(gx +  4);
    float4 xa2 = *(const float4*)(gx +  8), xa3 = *(const float4*)(gx + 12);
    float4 xb0 = *(const float4*)(gx + 64), xb1 = *(const float4*)(gx + 68);
    float4 xb2 = *(const float4*)(gx + 72), xb3 = *(const float4*)(gx + 76);
    float4 w0a = *(const float4*)(wfp +  0), w0b = *(const float4*)(wfp +  4);
    float4 w1a = *(const float4*)(wfp + 32), w1b = *(const float4*)(wfp + 36);
    float4 w2a = *(const float4*)(wfp + 64), w2b = *(const float4*)(wfp + 68);
    float4 w3a = *(const float4*)(wfp + 96), w3b = *(const float4*)(wfp + 100);

#define STEPBODY(RD, BH, BL)                                                 \
    {                                                                        \
        half8v a0h = *(const half8v*)&Ah[PB_][   0 + RD];                    \
        half8v a0l = *(const half8v*)&Al[PB_][   0 + RD];                    \
        half8v a1h = *(const half8v*)&Ah[PB_][1024 + RD];                    \
        half8v a1l = *(const half8v*)&Al[PB_][1024 + RD];                    \
        half8v a2h = *(const half8v*)&Ah[PB_][2048 + RD];                    \
        half8v a2l = *(const half8v*)&Al[PB_][2048 + RD];                    \
        half8v a3h = *(const half8v*)&Ah[PB_][3072 + RD];                    \
        half8v a3l = *(const half8v*)&Al[PB_][3072 + RD];                    \
        acc0 = MFMA16(a0l, BH, acc0);                                        \
        acc0 = MFMA16(a0h, BL, acc0);                                        \
        acc0 = MFMA16(a0h, BH, acc0);                                        \
        acc1 = MFMA16(a1l, BH, acc1);                                        \
        acc1 = MFMA16(a1h, BL, acc1);                                        \
        acc1 = MFMA16(a1h, BH, acc1);                                        \
        acc2 = MFMA16(a2l, BH, acc2);                                        \
        acc2 = MFMA16(a2h, BL, acc2);                                        \
        acc2 = MFMA16(a2h, BH, acc2);                                        \
        acc3 = MFMA16(a3l, BH, acc3);                                        \
        acc3 = MFMA16(a3h, BL, acc3);                                        \
        acc3 = MFMA16(a3h, BH, acc3);                                        \
    }

    // ONE barrier per chunk (head). Dbuf ordering proof:
    // [write P0] bar [read P0 | write P1] bar [read P1 | write P0] ...
    // writes of a buffer are always one barrier after its last reads.
#define CHUNK(ch, X0, X1, X2, X3, PB, WAa, WAb, WBa, WBb)                   \
    {                                                                        \
        const int PB_ = (PB);                                                \
        half8v h_, l_;                                                       \
        cvt8(X0, X1, h_, l_);                                                \
        *(half8v*)&Ah[PB_][off0] = h_;  *(half8v*)&Al[PB_][off0] = l_;       \
        cvt8(X2, X3, h_, l_);                                                \
        *(half8v*)&Ah[PB_][off1] = h_;  *(half8v*)&Al[PB_][off1] = l_;       \
        const int cf = ((ch) + 2 < NCH) ? (ch) + 2 : 0;                      \
        X0 = *(const float4*)(gx + cf * 64 +  0);                            \
        X1 = *(const float4*)(gx + cf * 64 +  4);                            \
        X2 = *(const float4*)(gx + cf * 64 +  8);                            \
        X3 = *(const float4*)(gx + cf * 64 + 12);                            \
        __builtin_amdgcn_sched_barrier(0);  /* pin refill issue point */     \
        asm volatile("s_waitcnt lgkmcnt(0)" ::: "memory");                   \
        __builtin_amdgcn_s_barrier();                                        \
        __builtin_amdgcn_sched_barrier(0);  /* no ds_read hoist above bar */ \
        {   /* step Sg = 2*ch */                                             \
            half8v bh, bl;                                                   \
            cvt8(WAa, WAb, bh, bl);                                          \
            const int SgN = (2 * (ch) + 4) & (NS - 1);                       \
            WAa = *(const float4*)(wfp + SgN * 32);                          \
            WAb = *(const float4*)(wfp + SgN * 32 + 4);                      \
            STEPBODY(rd0, bh, bl)                                            \
        }                                                                    \
        {   /* step Sg = 2*ch+1 */                                           \
            half8v bh, bl;                                                   \
            cvt8(WBa, WBb, bh, bl);                                          \
            const int SgN = (2 * (ch) + 5) & (NS - 1);                       \
            WBa = *(const float4*)(wfp + SgN * 32);                          \
            WBb = *(const float4*)(wfp + SgN * 32 + 4);                      \
            STEPBODY(rd1, bh, bl)                                            \
        }                                                                    \
    }

    for (int cb = 0; cb < NCH; cb += 2) {
        CHUNK(cb + 0, xa0, xa1, xa2, xa3, 0, w0a, w0b, w1a, w1b);
        CHUNK(cb + 1, xb0, xb1, xb2, xb3, 1, w2a, w2b, w3a, w3b);
    }
#undef CHUNK
#undef STEPBODY

    // ---- C layout: row m=(lane>>4)*4+rr, col n=lane&15 (m89/r5-verified) ----
    {
        const int qr = lane >> 4;
        const int nl = lane & 15;
        #pragma unroll
        for (int rr = 0; rr < 4; ++rr) {
            const int mm = qr * 4 + rr;
            lgt[ 0 + mm][wv * 16 + nl] = acc0[rr];
            lgt[16 + mm][wv * 16 + nl] = acc1[rr];
            lgt[32 + mm][wv * 16 + nl] = acc2[rr];
            lgt[48 + mm][wv * 16 + nl] = acc3[rr];
        }
    }
    __syncthreads();

    // ---- softmax + top-2: 8 threads/token, 2 passes of 32 tokens ----
    for (int pass = 0; pass < 2; ++pass) {
        const int m = pass * 32 + (tid >> 3);
        const int j = tid & 7;
        float l[8];
        #pragma unroll
        for (int i = 0; i < 8; ++i) l[i] = lgt[m][j * 8 + i];

        float mx = l[0];
        #pragma unroll
        for (int i = 1; i < 8; ++i) mx = fmaxf(mx, l[i]);
        #pragma unroll
        for (int off = 1; off < 8; off <<= 1) mx = fmaxf(mx, __shfl_xor(mx, off, 8));

        float ev[8];
        float zs = 0.f;
        float v1 = -INFINITY, v2 = -INFINITY;
        int i1 = 0, i2 = 0;
        #pragma unroll
        for (int i = 0; i < 8; ++i) {
            ev[i] = __expf(l[i] - mx);
            zs += ev[i];
            int e = j * 8 + i;
            if (l[i] > v1)      { v2 = v1; i2 = i1; v1 = l[i]; i1 = e; }
            else if (l[i] > v2) { v2 = l[i]; i2 = e; }
        }
        #pragma unroll
        for (int off = 1; off < 8; off <<= 1) zs += __shfl_xor(zs, off, 8);

        // merge top-2 across 8 lanes (value desc, index asc on ties = lax.top_k)
        #pragma unroll
        for (int off = 1; off < 8; off <<= 1) {
            float ov1 = __shfl_xor(v1, off, 8);
            int   oi1 = __shfl_xor(i1, off, 8);
            float ov2 = __shfl_xor(v2, off, 8);
            int   oi2 = __shfl_xor(i2, off, 8);
            bool afirst = (v1 > ov1) || (v1 == ov1 && i1 < oi1);
            if (afirst) {
                bool t = (v2 > ov1) || (v2 == ov1 && i2 < oi1);
                v2 = t ? v2 : ov1;
                i2 = t ? i2 : oi1;
            } else {
                bool t = (ov2 > v1) || (ov2 == v1 && oi2 < i1);
                v2 = t ? ov2 : v1;
                i2 = t ? oi2 : i1;
                v1 = ov1;
                i1 = oi1;
            }
        }

        const float invz = 1.0f / zs;
        if (j == 0) {
            float p1 = invz;                      // v1 == mx exactly
            float p2 = __expf(v2 - mx) * invz;
            float sden = p1 + p2 + 1e-9f;
            int tokg = m0 + m;
            out[tokg * 2 + 0] = (float)i1;
            out[tokg * 2 + 1] = (float)i2;
            out[32768 + tokg * 2 + 0] = p1 / sden;
            out[32768 + tokg * 2 + 1] = p2 / sden;
            atomicAdd(&cnt[i1], 1.0f);
            atomicAdd(&cnt[i2], 1.0f);
        }

        // probs writeback (own slots only)
        #pragma unroll
        for (int i = 0; i < 8; ++i) lgt[m][j * 8 + i] = ev[i] * invz;
    }
    __syncthreads();

    // global accumulators (accg zeroed by host-side memset each launch)
    if (tid < NEXP) {
        atomicAdd(&accg[tid], cnt[tid]);
    } else if (tid < 128) {
        int e = tid - 64;
        float s = 0.f;
        #pragma unroll
        for (int t = 0; t < TMB; ++t) s += lgt[t][e];
        atomicAdd(&accg[64 + e], s);
    }
    __syncthreads();

    // ---- last-block aux finalize (device-scope ticket) ----
    if (tid == 0) {
        __threadfence();   // release: our accg atomics visible before ticket
        unsigned int old = atomicAdd((unsigned int*)(accg + 128), 1u);
        lastBlk = (old == NBLK - 1) ? 1 : 0;
    }
    __syncthreads();
    if (lastBlk && tid < 64) {
        __threadfence();   // acquire: invalidate L1 before reading accg
        const volatile float* ag = accg;
        float c = ag[tid];
        float p = ag[64 + tid];
        float term = (c / (float)(NTOK * 2)) * (p / (float)NTOK);
        #pragma unroll
        for (int off = 1; off < 64; off <<= 1) term += __shfl_xor(term, off, 64);
        if (tid == 0) out[65536] = 0.01f * (float)NEXP * term;
    }
}

extern "C" void kernel_launch(void* const* d_in, const int* in_sizes, int n_in,
                              void* d_out, int out_size, void* d_ws, size_t ws_size,
                              hipStream_t stream) {
    const float* x = (const float*)d_in[0];   // [4,4096,2048]
    const float* W = (const float*)d_in[1];   // [64,2048]
    float* out  = (float*)d_out;              // 65537 floats
    float* accg = (float*)d_ws;               // 128 floats + ticket

    hipMemsetAsync(accg, 0, 1024, stream);    // counts, probsums, ticket
    router_kernel<<<NBLK, 256, 0, stream>>>(x, W, accg, out);
}

// Round 12
// 220.745 us; speedup vs baseline: 1.0187x; 1.0187x over previous
//
#include <hip/hip_runtime.h>
#include <math.h>

// TopKRouter: x[16384,2048] fp32, W[64,2048] fp32
// out: [0..32767] top2 indices (as float), [32768..65535] gates, [65536] aux
// Split-fp16 MFMA (3-term: xh*wh + xh*wl + xl*wh).
// R12: ALL-LDS pipeline, zero register rings. Diagnosis: R3 and R11 both
// report VGPR_Count=72 < the ~90 the named-reg rings need -> the allocator
// spills every register pipeline to scratch; at 1 wave/SIMD those scratch
// round-trips are the session-long ~65-90us invariant. Fix: both x and W
// staged via global_load_lds (no dest VGPRs -> nothing to spill):
//   TMB=64, 256 blocks (R7's 1024 VMEM instrs/CU), chunk=128 floats,
//   16 gload_lds/wave/chunk (8 x + 8 W, 1KB each, fp32, frag-granule order,
//   involution swizzle p=g^((g>>4)&7) applied on the per-lane SOURCE addr),
//   double-buffered 128KB LDS, one __syncthreads per chunk (its vmcnt(0)
//   drain is exactly "my stages done" -- all VMEM is staging now),
//   cvt fp32->(h,l) fp16 at read (same values, absmax-identical numerics).
// Keeps R10 fusion: no prep kernel, device-ticket aux finalize, memset accg.
#define NTOK 16384
#define DDIM 2048
#define NEXP 64
#define TMB  64                 // tokens per block (4 MFMA M-tiles)
#define NBLK (NTOK / TMB)       // 256 blocks -> 1 block/CU
#define CHF  128                // floats per chunk per row
#define NCHK (DDIM / CHF)       // 16 chunks
                                // 4 K32 steps per chunk

typedef _Float16 half8v __attribute__((ext_vector_type(8)));
typedef float    f32x4  __attribute__((ext_vector_type(4)));

#define MFMA16(a, b, c) __builtin_amdgcn_mfma_f32_16x16x32_f16((a), (b), (c), 0, 0, 0)

__device__ __forceinline__ void stage16(const void* g, void* l) {
    __builtin_amdgcn_global_load_lds(
        (const __attribute__((address_space(1))) unsigned int*)g,
        (__attribute__((address_space(3))) unsigned int*)l, 16, 0, 0);
}

// convert 8 consecutive fp32 -> (high fp16, residual fp16)
__device__ __forceinline__ void cvt8(float4 a, float4 b, half8v& h, half8v& l) {
    h[0]=(_Float16)a.x; l[0]=(_Float16)(a.x-(float)h[0]);
    h[1]=(_Float16)a.y; l[1]=(_Float16)(a.y-(float)h[1]);
    h[2]=(_Float16)a.z; l[2]=(_Float16)(a.z-(float)h[2]);
    h[3]=(_Float16)a.w; l[3]=(_Float16)(a.w-(float)h[3]);
    h[4]=(_Float16)b.x; l[4]=(_Float16)(b.x-(float)h[4]);
    h[5]=(_Float16)b.y; l[5]=(_Float16)(b.y-(float)h[5]);
    h[6]=(_Float16)b.z; l[6]=(_Float16)(b.z-(float)h[6]);
    h[7]=(_Float16)b.w; l[7]=(_Float16)(b.w-(float)h[7]);
}

__global__ __launch_bounds__(256, 1) void router_kernel(
    const float* __restrict__ x, const float* __restrict__ W,
    float* __restrict__ accg, float* __restrict__ out)
{
    // frag-granule fp32, double-buffered. Per buffer: [4 tiles][2048 floats]
    // granule g = S*64 + q*16 + tok (8 floats) stored at pos p = g^((g>>4)&7).
    __shared__ __align__(16) float Xs[2][8192];     // 64 KB (x: 4 token-tiles)
    __shared__ __align__(16) float Ws[2][8192];     // 64 KB (W: 4 expert-tiles)
    __shared__ float lgt[TMB][NEXP + 1];            // 16.6 KB
    __shared__ float cnt[NEXP];
    __shared__ int lastBlk;

    const int tid  = threadIdx.x;
    const int lane = tid & 63;
    const int wv   = __builtin_amdgcn_readfirstlane(tid >> 6);  // 0..3
    const int m0   = blockIdx.x * TMB;

    if (tid < NEXP) cnt[tid] = 0.0f;

    // ---- staging: wave wv stages x token-tile wv and W expert-tile wv.
    // Instr i (0..7) fills LDS granules p = i*32 .. i*32+31 (1 KB linear).
    // Lane l supplies half-granule: p = i*32 + (l>>1), 16B half h = l&1.
    // Source (involution): g = p ^ ((p>>4)&7); row-in-tile = g&15,
    // kk = (g>>6)*32 + ((g>>4)&3)*8; o = row*2048 + kk + h*4 (floats).
#define MKOFF(i) ({ int p_ = (i)*32 + (lane >> 1);                           \
                    int g_ = p_ ^ ((p_ >> 4) & 7);                           \
                    (g_ & 15)*2048 + (g_ >> 6)*32 + ((g_ >> 4) & 3)*8        \
                    + (lane & 1)*4; })
    const int o0 = MKOFF(0), o1 = MKOFF(1), o2 = MKOFF(2), o3 = MKOFF(3);
    const int o4 = MKOFF(4), o5 = MKOFF(5), o6 = MKOFF(6), o7 = MKOFF(7);
#undef MKOFF

    const float* bx = x + (size_t)(m0 + wv * 16) * DDIM;   // + o_i + cc*128
    const float* bw = W + (size_t)(wv * 16) * DDIM;

    // ---- read-side: step S granule g = S*64 + (l>>4)*16 + (l&15),
    // float offset pf = (g ^ ((g>>4)&7)) * 8 (per tile add t*2048).
#define MKP(S) ({ int g_ = (S)*64 + ((lane >> 4) << 4) + (lane & 15);        \
                  (g_ ^ ((g_ >> 4) & 7)) * 8; })
    const int pf0 = MKP(0), pf1 = MKP(1), pf2 = MKP(2), pf3 = MKP(3);
#undef MKP

    f32x4 acc0 = {0.f,0.f,0.f,0.f}, acc1 = {0.f,0.f,0.f,0.f};
    f32x4 acc2 = {0.f,0.f,0.f,0.f}, acc3 = {0.f,0.f,0.f,0.f};

#define STAGE(cc, B)                                                         \
    {                                                                        \
        const float* bx_ = bx + (size_t)(cc) * CHF;                          \
        const float* bw_ = bw + (size_t)(cc) * CHF;                          \
        float* dx_ = &Xs[B][wv * 2048];                                      \
        float* dw_ = &Ws[B][wv * 2048];                                      \
        stage16(bx_ + o0, dx_ +    0);  stage16(bw_ + o0, dw_ +    0);       \
        stage16(bx_ + o1, dx_ +  256);  stage16(bw_ + o1, dw_ +  256);       \
        stage16(bx_ + o2, dx_ +  512);  stage16(bw_ + o2, dw_ +  512);       \
        stage16(bx_ + o3, dx_ +  768);  stage16(bw_ + o3, dw_ +  768);       \
        stage16(bx_ + o4, dx_ + 1024);  stage16(bw_ + o4, dw_ + 1024);       \
        stage16(bx_ + o5, dx_ + 1280);  stage16(bw_ + o5, dw_ + 1280);       \
        stage16(bx_ + o6, dx_ + 1536);  stage16(bw_ + o6, dw_ + 1536);       \
        stage16(bx_ + o7, dx_ + 1792);  stage16(bw_ + o7, dw_ + 1792);       \
    }

#define STEP(PB, PF)                                                         \
    {                                                                        \
        float4 v0, v1;                                                       \
        half8v bh, bl;                                                       \
        v0 = *(const float4*)&Ws[PB][wv * 2048 + (PF)];                      \
        v1 = *(const float4*)&Ws[PB][wv * 2048 + (PF) + 4];                  \
        cvt8(v0, v1, bh, bl);                                                \
        half8v a0h,a0l,a1h,a1l,a2h,a2l,a3h,a3l;                              \
        v0 = *(const float4*)&Xs[PB][       (PF)];                           \
        v1 = *(const float4*)&Xs[PB][       (PF) + 4];  cvt8(v0,v1,a0h,a0l); \
        v0 = *(const float4*)&Xs[PB][2048 + (PF)];                           \
        v1 = *(const float4*)&Xs[PB][2048 + (PF) + 4];  cvt8(v0,v1,a1h,a1l); \
        v0 = *(const float4*)&Xs[PB][4096 + (PF)];                           \
        v1 = *(const float4*)&Xs[PB][4096 + (PF) + 4];  cvt8(v0,v1,a2h,a2l); \
        v0 = *(const float4*)&Xs[PB][6144 + (PF)];                           \
        v1 = *(const float4*)&Xs[PB][6144 + (PF) + 4];  cvt8(v0,v1,a3h,a3l); \
        acc0 = MFMA16(a0l, bh, acc0);                                        \
        acc0 = MFMA16(a0h, bl, acc0);                                        \
        acc0 = MFMA16(a0h, bh, acc0);                                        \
        acc1 = MFMA16(a1l, bh, acc1);                                        \
        acc1 = MFMA16(a1h, bl, acc1);                                        \
        acc1 = MFMA16(a1h, bh, acc1);                                        \
        acc2 = MFMA16(a2l, bh, acc2);                                        \
        acc2 = MFMA16(a2h, bl, acc2);                                        \
        acc2 = MFMA16(a2h, bh, acc2);                                        \
        acc3 = MFMA16(a3l, bh, acc3);                                        \
        acc3 = MFMA16(a3h, bl, acc3);                                        \
        acc3 = MFMA16(a3h, bh, acc3);                                        \
    }

#define COMPUTE(PB)                                                          \
    STEP(PB, pf0) STEP(PB, pf1) STEP(PB, pf2) STEP(PB, pf3)

    // prologue: stage chunk 0 into buf 0
    STAGE(0, 0);

    for (int cb = 0; cb < NCHK; cb += 2) {
        __syncthreads();                 // stages(cb) done; buf1 free
        STAGE(cb + 1, 1);                // issue next (flies under compute)
        COMPUTE(0);                      // chunk cb from buf 0
        __syncthreads();                 // stages(cb+1) done; buf0 free
        if (cb + 2 < NCHK) STAGE(cb + 2, 0);
        COMPUTE(1);                      // chunk cb+1 from buf 1
    }
#undef COMPUTE
#undef STEP
#undef STAGE

    // ---- C layout: row m=(lane>>4)*4+rr, col n=lane&15 (m89/r5-verified) ----
    {
        const int qr = lane >> 4;
        const int nl = lane & 15;
        #pragma unroll
        for (int rr = 0; rr < 4; ++rr) {
            const int mm = qr * 4 + rr;
            lgt[ 0 + mm][wv * 16 + nl] = acc0[rr];
            lgt[16 + mm][wv * 16 + nl] = acc1[rr];
            lgt[32 + mm][wv * 16 + nl] = acc2[rr];
            lgt[48 + mm][wv * 16 + nl] = acc3[rr];
        }
    }
    __syncthreads();

    // ---- softmax + top-2: 8 threads/token, 2 passes of 32 tokens ----
    for (int pass = 0; pass < 2; ++pass) {
        const int m = pass * 32 + (tid >> 3);
        const int j = tid & 7;
        float l[8];
        #pragma unroll
        for (int i = 0; i < 8; ++i) l[i] = lgt[m][j * 8 + i];

        float mx = l[0];
        #pragma unroll
        for (int i = 1; i < 8; ++i) mx = fmaxf(mx, l[i]);
        #pragma unroll
        for (int off = 1; off < 8; off <<= 1) mx = fmaxf(mx, __shfl_xor(mx, off, 8));

        float ev[8];
        float zs = 0.f;
        float v1 = -INFINITY, v2 = -INFINITY;
        int i1 = 0, i2 = 0;
        #pragma unroll
        for (int i = 0; i < 8; ++i) {
            ev[i] = __expf(l[i] - mx);
            zs += ev[i];
            int e = j * 8 + i;
            if (l[i] > v1)      { v2 = v1; i2 = i1; v1 = l[i]; i1 = e; }
            else if (l[i] > v2) { v2 = l[i]; i2 = e; }
        }
        #pragma unroll
        for (int off = 1; off < 8; off <<= 1) zs += __shfl_xor(zs, off, 8);

        // merge top-2 across 8 lanes (value desc, index asc on ties = lax.top_k)
        #pragma unroll
        for (int off = 1; off < 8; off <<= 1) {
            float ov1 = __shfl_xor(v1, off, 8);
            int   oi1 = __shfl_xor(i1, off, 8);
            float ov2 = __shfl_xor(v2, off, 8);
            int   oi2 = __shfl_xor(i2, off, 8);
            bool afirst = (v1 > ov1) || (v1 == ov1 && i1 < oi1);
            if (afirst) {
                bool t = (v2 > ov1) || (v2 == ov1 && i2 < oi1);
                v2 = t ? v2 : ov1;
                i2 = t ? i2 : oi1;
            } else {
                bool t = (ov2 > v1) || (ov2 == v1 && oi2 < i1);
                v2 = t ? ov2 : v1;
                i2 = t ? oi2 : i1;
                v1 = ov1;
                i1 = oi1;
            }
        }

        const float invz = 1.0f / zs;
        if (j == 0) {
            float p1 = invz;                      // v1 == mx exactly
            float p2 = __expf(v2 - mx) * invz;
            float sden = p1 + p2 + 1e-9f;
            int tokg = m0 + m;
            out[tokg * 2 + 0] = (float)i1;
            out[tokg * 2 + 1] = (float)i2;
            out[32768 + tokg * 2 + 0] = p1 / sden;
            out[32768 + tokg * 2 + 1] = p2 / sden;
            atomicAdd(&cnt[i1], 1.0f);
            atomicAdd(&cnt[i2], 1.0f);
        }

        // probs writeback (own slots only)
        #pragma unroll
        for (int i = 0; i < 8; ++i) lgt[m][j * 8 + i] = ev[i] * invz;
    }
    __syncthreads();

    // global accumulators (accg zeroed by host-side memset each launch)
    if (tid < NEXP) {
        atomicAdd(&accg[tid], cnt[tid]);
    } else if (tid < 128) {
        int e = tid - 64;
        float s = 0.f;
        #pragma unroll
        for (int t = 0; t < TMB; ++t) s += lgt[t][e];
        atomicAdd(&accg[64 + e], s);
    }
    __syncthreads();

    // ---- last-block aux finalize (device-scope ticket) ----
    if (tid == 0) {
        __threadfence();   // release: our accg atomics visible before ticket
        unsigned int old = atomicAdd((unsigned int*)(accg + 128), 1u);
        lastBlk = (old == NBLK - 1) ? 1 : 0;
    }
    __syncthreads();
    if (lastBlk && tid < 64) {
        __threadfence();   // acquire: invalidate L1 before reading accg
        const volatile float* ag = accg;
        float c = ag[tid];
        float p = ag[64 + tid];
        float term = (c / (float)(NTOK * 2)) * (p / (float)NTOK);
        #pragma unroll
        for (int off = 1; off < 64; off <<= 1) term += __shfl_xor(term, off, 64);
        if (tid == 0) out[65536] = 0.01f * (float)NEXP * term;
    }
}

extern "C" void kernel_launch(void* const* d_in, const int* in_sizes, int n_in,
                              void* d_out, int out_size, void* d_ws, size_t ws_size,
                              hipStream_t stream) {
    const float* x = (const float*)d_in[0];   // [4,4096,2048]
    const float* W = (const float*)d_in[1];   // [64,2048]
    float* out  = (float*)d_out;              // 65537 floats
    float* accg = (float*)d_ws;               // 128 floats + ticket

    hipMemsetAsync(accg, 0, 1024, stream);    // counts, probsums, ticket
    router_kernel<<<NBLK, 256, 0, stream>>>(x, W, accg, out);
}